// Round 18
// baseline (33.875 us; speedup 1.0000x reference)
//
#include <hip/hip_runtime.h>

// Head: fused GEMM (M=204800, K=128, N=84->96) + DFL softmax + box decode + sigmoid.
// R18 = R17 + (a) bias hoisted to registers (bl[6]) -> ZERO per-tile LDS reads,
//             (b) nontemporal x loads + out stores (each byte touched once).
// Kept: wf reg hoist at (256,1) (no spill), packed-b64 staging, t0/t1 preload,
// 2-deep pipeline, lane-local softmax, scdfl exchange, exp2/rcp/cvt_pkrtz diet.

typedef _Float16 half8 __attribute__((ext_vector_type(8)));
typedef _Float16 half4 __attribute__((ext_vector_type(4)));
typedef __fp16  fp16x2 __attribute__((ext_vector_type(2)));
typedef float f32x4v __attribute__((ext_vector_type(4)));

constexpr int Cc = 128;
constexpr int NPAD = 96;
constexpr int WT_STRIDE = 136;
constexpr int NWAVES = 2048;         // 512 blocks * 4 waves
constexpr float LOG2E = 1.44269504088896f;

union H8 { half8 h; fp16x2 p[4]; };

__device__ __forceinline__ float sigm(float v) {
    return __builtin_amdgcn_rcpf(1.f + __builtin_amdgcn_exp2f(-LOG2E * v));
}

__global__ __launch_bounds__(256, 1)
void head_kernel(const float* __restrict__ x,
                 const float* __restrict__ w_box,
                 const float* __restrict__ b_box,
                 const float* __restrict__ w_cls,
                 const float* __restrict__ b_cls,
                 const int*   __restrict__ stride_p,
                 float* __restrict__ out)
{
    __shared__ __align__(16) _Float16 Wt[NPAD][WT_STRIDE]; // permuted box rows
    __shared__ __align__(16) float bias_s[NPAD];           // same permuted order
    __shared__ __align__(16) float scdfl[4][16][4];        // per-wave dfl exchange (1KB)

    const int tid  = threadIdx.x;
    const int wave = tid >> 6;      // 0..3
    const int lane = tid & 63;
    const int c    = lane & 15;     // B spatial-row / D col
    const int g    = lane >> 4;     // D row = 4g+reg; g = DFL distribution id

    const int wid = blockIdx.x * 4 + wave;       // 0..2047
    const int t0 = wid,              t1 = wid + NWAVES;
    const int t2 = wid + 2 * NWAVES, t3 = wid + 3 * NWAVES;
    const int t4 = wid + 4 * NWAVES, t5 = wid + 5 * NWAVES;   // [0, 12288)
    const bool heavy = (wave == (blockIdx.x & 3));            // 1 per block
    const int t6 = 6 * NWAVES + blockIdx.x;                   // [12288, 12800)

    f32x4v xvA[4][2], xvB[4][2];

    auto load_tile = [&](f32x4v (&xv)[4][2], int tile) {
        const float* xb = x + (size_t)(tile * 16 + c) * Cc + g * 8;
        #pragma unroll
        for (int ks = 0; ks < 4; ++ks) {
            const float* p = xb + ks * 32;
            xv[ks][0] = __builtin_nontemporal_load((const f32x4v*)p);
            xv[ks][1] = __builtin_nontemporal_load((const f32x4v*)(p + 4));
        }
        __builtin_amdgcn_sched_barrier(0);   // pin load issue here
    };

    // ---- issue first 2 tiles' loads BEFORE staging (overlap prologue) ----
    load_tile(xvA, t0);
    load_tile(xvB, t1);

    // ---- stage Wt (box rows PERMUTED: row t*16+4f+r <- ch f*16+4t+r) ----
    for (int i = tid; i < 512; i += 256) {
        int ch0 = (i >> 5) << 2;               // 0,4,..,60
        int k0  = (i & 31) << 2;               // 0,4,..,124
        int f   = ch0 >> 4;
        int b0  = ch0 & 15;
        int R0  = (b0 >> 2) * 16 + (f << 2);   // t*16 + 4f
        f32x4v v0 = *(const f32x4v*)&w_box[(k0 + 0) * 64 + ch0];
        f32x4v v1 = *(const f32x4v*)&w_box[(k0 + 1) * 64 + ch0];
        f32x4v v2 = *(const f32x4v*)&w_box[(k0 + 2) * 64 + ch0];
        f32x4v v3 = *(const f32x4v*)&w_box[(k0 + 3) * 64 + ch0];
        #pragma unroll
        for (int r = 0; r < 4; ++r) {
            half4 h = { (_Float16)v0[r], (_Float16)v1[r], (_Float16)v2[r], (_Float16)v3[r] };
            *(half4*)&Wt[R0 + r][k0] = h;
        }
    }
    for (int i = tid; i < 160; i += 256) {
        int ch0 = (i / 32) << 2;               // 0,4,8,12,16
        int k0  = (i & 31) << 2;
        f32x4v v0 = *(const f32x4v*)&w_cls[(k0 + 0) * 20 + ch0];
        f32x4v v1 = *(const f32x4v*)&w_cls[(k0 + 1) * 20 + ch0];
        f32x4v v2 = *(const f32x4v*)&w_cls[(k0 + 2) * 20 + ch0];
        f32x4v v3 = *(const f32x4v*)&w_cls[(k0 + 3) * 20 + ch0];
        #pragma unroll
        for (int r = 0; r < 4; ++r) {
            half4 h = { (_Float16)v0[r], (_Float16)v1[r], (_Float16)v2[r], (_Float16)v3[r] };
            *(half4*)&Wt[64 + ch0 + r][k0] = h;
        }
    }
    for (int i = tid; i < 12 * 16; i += 256) {   // zero pad rows 84..95 (b128)
        int ch = 84 + (i >> 4);
        int k0 = (i & 15) << 3;
        *(f32x4v*)&Wt[ch][k0] = (f32x4v){0.f, 0.f, 0.f, 0.f};
    }
    if (tid < 64) {                              // box bias, permuted
        int f = tid >> 4, b = tid & 15;
        bias_s[(b >> 2) * 16 + (f << 2) + (b & 3)] = b_box[tid];
    } else if (tid < 96) {
        bias_s[tid] = (tid < 84) ? b_cls[tid - 64] : 0.f;
    }
    __syncthreads();

    // ---- hoist weight fragments AND bias into registers ONCE ----
    half8 wf[4][6];
    #pragma unroll
    for (int ks = 0; ks < 4; ++ks)
        #pragma unroll
        for (int nt = 0; nt < 6; ++nt)
            wf[ks][nt] = *(const half8*)&Wt[nt * 16 + c][ks * 32 + g * 8];

    f32x4v bl[6];
    #pragma unroll
    for (int nt = 0; nt < 6; ++nt)
        bl[nt] = *(const f32x4v*)&bias_s[nt * 16 + g * 4];

    const float sf = (float)stride_p[0];

    auto compute_tile = [&](f32x4v (&xv)[4][2], int tile) {
        f32x4v acc[6];
        #pragma unroll
        for (int nt = 0; nt < 6; ++nt)
            acc[nt] = bl[nt];                      // register init, zero LDS

        #pragma unroll
        for (int ks = 0; ks < 4; ++ks) {
            f32x4v lo = xv[ks][0], hi = xv[ks][1];
            H8 bu;
            bu.p[0] = __builtin_amdgcn_cvt_pkrtz(lo[0], lo[1]);
            bu.p[1] = __builtin_amdgcn_cvt_pkrtz(lo[2], lo[3]);
            bu.p[2] = __builtin_amdgcn_cvt_pkrtz(hi[0], hi[1]);
            bu.p[3] = __builtin_amdgcn_cvt_pkrtz(hi[2], hi[3]);
            #pragma unroll
            for (int nt = 0; nt < 6; ++nt)
                acc[nt] = __builtin_amdgcn_mfma_f32_16x16x32_f16(wf[ks][nt], bu.h, acc[nt], 0, 0, 0);
        }

        // lane-local DFL softmax over all 16 bins of distribution g
        float s = 0.f, ws = 0.f;
        #pragma unroll
        for (int t = 0; t < 4; ++t) {
            f32x4v v = acc[t];
            float e0 = __builtin_amdgcn_exp2f(LOG2E * v[0]);
            float e1 = __builtin_amdgcn_exp2f(LOG2E * v[1]);
            float e2 = __builtin_amdgcn_exp2f(LOG2E * v[2]);
            float e3 = __builtin_amdgcn_exp2f(LOG2E * v[3]);
            s  += e0 + e1 + e2 + e3;
            ws += (float)(4 * t) * e0 + (float)(4 * t + 1) * e1
                + (float)(4 * t + 2) * e2 + (float)(4 * t + 3) * e3;
        }
        const float dfl = ws * __builtin_amdgcn_rcpf(s);

        // exchange dfl across g within the wave (tiny LDS round-trip, no shfl)
        scdfl[wave][c][g] = dfl;
        f32x4v db = *(const f32x4v*)&scdfl[wave][c][0];

        const int pos0 = (tile % 400) * 16;    // rows stay in one y-line (80 = 5*16)
        const int yp   = pos0 / 80;
        const int xq   = (pos0 - 80 * yp) + c;
        const float ax = ((float)xq + 0.5f) * sf;
        const float ay = ((float)yp + 0.5f) * sf;
        const float w2 = db[2] - db[0], w3 = db[3] - db[1];

        float* op = out + (size_t)(tile * 16 + c) * 24;

        f32x4v clsA = { sigm(acc[4][0]), sigm(acc[4][1]), sigm(acc[4][2]), sigm(acc[4][3]) };
        __builtin_nontemporal_store(clsA, (f32x4v*)(op + 4 + 4 * g));
        if (g == 0) {
            f32x4v box = { ax + 0.5f * w2, ay + 0.5f * w3, w2, w3 };
            __builtin_nontemporal_store(box, (f32x4v*)op);
            f32x4v clsB = { sigm(acc[5][0]), sigm(acc[5][1]), sigm(acc[5][2]), sigm(acc[5][3]) };
            __builtin_nontemporal_store(clsB, (f32x4v*)(op + 20));
        }
    };

    // ---- 2-deep pipeline over 6-7 tiles ----
    compute_tile(xvA, t0);  load_tile(xvA, t2);
    compute_tile(xvB, t1);  load_tile(xvB, t3);
    compute_tile(xvA, t2);  load_tile(xvA, t4);
    compute_tile(xvB, t3);  load_tile(xvB, t5);
    compute_tile(xvA, t4);  if (heavy) load_tile(xvA, t6);
    compute_tile(xvB, t5);
    if (heavy) compute_tile(xvA, t6);
}

extern "C" void kernel_launch(void* const* d_in, const int* in_sizes, int n_in,
                              void* d_out, int out_size, void* d_ws, size_t ws_size,
                              hipStream_t stream) {
    const float* x      = (const float*)d_in[0];
    const float* w_box  = (const float*)d_in[1];
    const float* b_box  = (const float*)d_in[2];
    const float* w_cls  = (const float*)d_in[3];
    const float* b_cls  = (const float*)d_in[4];
    const int*   stride_p = (const int*)d_in[5];
    float* out = (float*)d_out;

    dim3 grid(512), block(256);
    hipLaunchKernelGGL(head_kernel, grid, block, 0, stream,
                       x, w_box, b_box, w_cls, b_cls, stride_p, out);
}

// Round 19
// 26.970 us; speedup vs baseline: 1.2560x; 1.2560x over previous
//
#include <hip/hip_runtime.h>

// Head: fused GEMM (M=204800, K=128, N=84->96) + DFL softmax + box decode + sigmoid.
// R19 = exact revert to R17 (best: 26.8us). R18's nontemporal hints broke L3
// residency of x across timed replays (-7us) -- reverted. Bias stays as LDS
// acc-init (compiler already promotes it; explicit hoist only added pressure).
//   - __launch_bounds__(256,1): no 128-VGPR heuristic cap -> wf hoist w/o spill
//   - wf[4][6] half8 read once per wave; main loop has ZERO LDS reads
//   - 2-deep pipeline; t0/t1 x-loads issued before weight staging
//   - packed ds_write_b64 staging; lane-local softmax; scdfl exchange
//   - exp2/rcp/cvt_pkrtz VALU diet

typedef _Float16 half8 __attribute__((ext_vector_type(8)));
typedef _Float16 half4 __attribute__((ext_vector_type(4)));
typedef __fp16  fp16x2 __attribute__((ext_vector_type(2)));
typedef float f32x4v __attribute__((ext_vector_type(4)));

constexpr int Cc = 128;
constexpr int NPAD = 96;
constexpr int WT_STRIDE = 136;       // f16; 272B row, 8B-aligned for b64 column writes
constexpr int NWAVES = 2048;         // 512 blocks * 4 waves
constexpr float LOG2E = 1.44269504088896f;

union H8 { half8 h; fp16x2 p[4]; };

__device__ __forceinline__ float sigm(float v) {
    return __builtin_amdgcn_rcpf(1.f + __builtin_amdgcn_exp2f(-LOG2E * v));
}

__global__ __launch_bounds__(256, 1)
void head_kernel(const float* __restrict__ x,
                 const float* __restrict__ w_box,
                 const float* __restrict__ b_box,
                 const float* __restrict__ w_cls,
                 const float* __restrict__ b_cls,
                 const int*   __restrict__ stride_p,
                 float* __restrict__ out)
{
    __shared__ __align__(16) _Float16 Wt[NPAD][WT_STRIDE]; // permuted box rows
    __shared__ __align__(16) float bias_s[NPAD];           // same permuted order
    __shared__ __align__(16) float scdfl[4][16][4];        // per-wave dfl exchange (1KB)

    const int tid  = threadIdx.x;
    const int wave = tid >> 6;      // 0..3
    const int lane = tid & 63;
    const int c    = lane & 15;     // B spatial-row / D col
    const int g    = lane >> 4;     // D row = 4g+reg; g = DFL distribution id

    const int wid = blockIdx.x * 4 + wave;       // 0..2047
    const int t0 = wid,              t1 = wid + NWAVES;
    const int t2 = wid + 2 * NWAVES, t3 = wid + 3 * NWAVES;
    const int t4 = wid + 4 * NWAVES, t5 = wid + 5 * NWAVES;   // [0, 12288)
    const bool heavy = (wave == (blockIdx.x & 3));            // 1 per block
    const int t6 = 6 * NWAVES + blockIdx.x;                   // [12288, 12800)

    f32x4v xvA[4][2], xvB[4][2];

    auto load_tile = [&](f32x4v (&xv)[4][2], int tile) {
        const float* xb = x + (size_t)(tile * 16 + c) * Cc + g * 8;
        #pragma unroll
        for (int ks = 0; ks < 4; ++ks) {
            const float* p = xb + ks * 32;
            xv[ks][0] = *(const f32x4v*)p;
            xv[ks][1] = *(const f32x4v*)(p + 4);
        }
        __builtin_amdgcn_sched_barrier(0);   // pin load issue here
    };

    // ---- issue first 2 tiles' loads BEFORE staging (overlap prologue) ----
    load_tile(xvA, t0);
    load_tile(xvB, t1);

    // ---- stage Wt (box rows PERMUTED: row t*16+4f+r <- ch f*16+4t+r) ----
    // box: 512 items = 16 ch0-groups x 32 k-groups; 4 k's packed per b64 write.
    for (int i = tid; i < 512; i += 256) {
        int ch0 = (i >> 5) << 2;               // 0,4,..,60
        int k0  = (i & 31) << 2;               // 0,4,..,124
        int f   = ch0 >> 4;
        int b0  = ch0 & 15;
        int R0  = (b0 >> 2) * 16 + (f << 2);   // t*16 + 4f
        f32x4v v0 = *(const f32x4v*)&w_box[(k0 + 0) * 64 + ch0];
        f32x4v v1 = *(const f32x4v*)&w_box[(k0 + 1) * 64 + ch0];
        f32x4v v2 = *(const f32x4v*)&w_box[(k0 + 2) * 64 + ch0];
        f32x4v v3 = *(const f32x4v*)&w_box[(k0 + 3) * 64 + ch0];
        #pragma unroll
        for (int r = 0; r < 4; ++r) {
            half4 h = { (_Float16)v0[r], (_Float16)v1[r], (_Float16)v2[r], (_Float16)v3[r] };
            *(half4*)&Wt[R0 + r][k0] = h;
        }
    }
    // cls: 160 items = 5 ch0-groups x 32 k-groups
    for (int i = tid; i < 160; i += 256) {
        int ch0 = (i / 32) << 2;               // 0,4,8,12,16
        int k0  = (i & 31) << 2;
        f32x4v v0 = *(const f32x4v*)&w_cls[(k0 + 0) * 20 + ch0];
        f32x4v v1 = *(const f32x4v*)&w_cls[(k0 + 1) * 20 + ch0];
        f32x4v v2 = *(const f32x4v*)&w_cls[(k0 + 2) * 20 + ch0];
        f32x4v v3 = *(const f32x4v*)&w_cls[(k0 + 3) * 20 + ch0];
        #pragma unroll
        for (int r = 0; r < 4; ++r) {
            half4 h = { (_Float16)v0[r], (_Float16)v1[r], (_Float16)v2[r], (_Float16)v3[r] };
            *(half4*)&Wt[64 + ch0 + r][k0] = h;
        }
    }
    // zero pad rows 84..95 (b128 chunks)
    for (int i = tid; i < 12 * 16; i += 256) {
        int ch = 84 + (i >> 4);
        int k0 = (i & 15) << 3;
        *(f32x4v*)&Wt[ch][k0] = (f32x4v){0.f, 0.f, 0.f, 0.f};
    }
    if (tid < 64) {                              // box bias, permuted
        int f = tid >> 4, b = tid & 15;
        bias_s[(b >> 2) * 16 + (f << 2) + (b & 3)] = b_box[tid];
    } else if (tid < 96) {
        bias_s[tid] = (tid < 84) ? b_cls[tid - 64] : 0.f;
    }
    __syncthreads();

    // ---- hoist weight fragments into registers ONCE (24 ds_read_b128) ----
    half8 wf[4][6];
    #pragma unroll
    for (int ks = 0; ks < 4; ++ks)
        #pragma unroll
        for (int nt = 0; nt < 6; ++nt)
            wf[ks][nt] = *(const half8*)&Wt[nt * 16 + c][ks * 32 + g * 8];

    const float sf = (float)stride_p[0];

    auto compute_tile = [&](f32x4v (&xv)[4][2], int tile) {
        f32x4v acc[6];
        #pragma unroll
        for (int nt = 0; nt < 6; ++nt)
            acc[nt] = *(const f32x4v*)&bias_s[nt * 16 + g * 4];

        #pragma unroll
        for (int ks = 0; ks < 4; ++ks) {
            f32x4v lo = xv[ks][0], hi = xv[ks][1];
            H8 bu;
            bu.p[0] = __builtin_amdgcn_cvt_pkrtz(lo[0], lo[1]);
            bu.p[1] = __builtin_amdgcn_cvt_pkrtz(lo[2], lo[3]);
            bu.p[2] = __builtin_amdgcn_cvt_pkrtz(hi[0], hi[1]);
            bu.p[3] = __builtin_amdgcn_cvt_pkrtz(hi[2], hi[3]);
            #pragma unroll
            for (int nt = 0; nt < 6; ++nt)
                acc[nt] = __builtin_amdgcn_mfma_f32_16x16x32_f16(wf[ks][nt], bu.h, acc[nt], 0, 0, 0);
        }

        // lane-local DFL softmax over all 16 bins of distribution g
        float s = 0.f, ws = 0.f;
        #pragma unroll
        for (int t = 0; t < 4; ++t) {
            f32x4v v = acc[t];
            float e0 = __builtin_amdgcn_exp2f(LOG2E * v[0]);
            float e1 = __builtin_amdgcn_exp2f(LOG2E * v[1]);
            float e2 = __builtin_amdgcn_exp2f(LOG2E * v[2]);
            float e3 = __builtin_amdgcn_exp2f(LOG2E * v[3]);
            s  += e0 + e1 + e2 + e3;
            ws += (float)(4 * t) * e0 + (float)(4 * t + 1) * e1
                + (float)(4 * t + 2) * e2 + (float)(4 * t + 3) * e3;
        }
        const float dfl = ws * __builtin_amdgcn_rcpf(s);

        // exchange dfl across g within the wave (tiny LDS round-trip, no shfl)
        scdfl[wave][c][g] = dfl;
        f32x4v db = *(const f32x4v*)&scdfl[wave][c][0];

        const int pos0 = (tile % 400) * 16;    // rows stay in one y-line (80 = 5*16)
        const int yp   = pos0 / 80;
        const int xq   = (pos0 - 80 * yp) + c;
        const float ax = ((float)xq + 0.5f) * sf;
        const float ay = ((float)yp + 0.5f) * sf;
        const float w2 = db[2] - db[0], w3 = db[3] - db[1];

        float* op = out + (size_t)(tile * 16 + c) * 24;

        f32x4v clsA = { sigm(acc[4][0]), sigm(acc[4][1]), sigm(acc[4][2]), sigm(acc[4][3]) };
        *(f32x4v*)(op + 4 + 4 * g) = clsA;
        if (g == 0) {
            f32x4v box = { ax + 0.5f * w2, ay + 0.5f * w3, w2, w3 };
            *(f32x4v*)op = box;
            f32x4v clsB = { sigm(acc[5][0]), sigm(acc[5][1]), sigm(acc[5][2]), sigm(acc[5][3]) };
            *(f32x4v*)(op + 20) = clsB;
        }
    };

    // ---- 2-deep pipeline over 6-7 tiles ----
    compute_tile(xvA, t0);  load_tile(xvA, t2);
    compute_tile(xvB, t1);  load_tile(xvB, t3);
    compute_tile(xvA, t2);  load_tile(xvA, t4);
    compute_tile(xvB, t3);  load_tile(xvB, t5);
    compute_tile(xvA, t4);  if (heavy) load_tile(xvA, t6);
    compute_tile(xvB, t5);
    if (heavy) compute_tile(xvA, t6);
}

extern "C" void kernel_launch(void* const* d_in, const int* in_sizes, int n_in,
                              void* d_out, int out_size, void* d_ws, size_t ws_size,
                              hipStream_t stream) {
    const float* x      = (const float*)d_in[0];
    const float* w_box  = (const float*)d_in[1];
    const float* b_box  = (const float*)d_in[2];
    const float* w_cls  = (const float*)d_in[3];
    const float* b_cls  = (const float*)d_in[4];
    const int*   stride_p = (const int*)d_in[5];
    float* out = (float*)d_out;

    dim3 grid(512), block(256);
    hipLaunchKernelGGL(head_kernel, grid, block, 0, stream,
                       x, w_box, b_box, w_cls, b_cls, stride_p, out);
}